// Round 4
// baseline (352.523 us; speedup 1.0000x reference)
//
#include <hip/hip_runtime.h>

// conv1d: out[b,i] = sum_{k<16,d<512} x[b,i+k,d] * w[k,d] + bias, zero-pad at end.
// Memory-bound: 256 MiB input, ~43 us HBM floor.
// R3: barrier-free register sliding window. Block = 512 thr (8 waves) owns 64
// outputs (4 chunks x 16); wave owns a 64-wide d-slice, lane owns ONE d ->
// filter w[16]=16 VGPR, acc[16]=16 VGPR, demand ~50 < the compiler's favored
// 64-VGPR allocation (spill trap of R0/R1 fired at demand 90-160). No LDS
// ring, no per-chunk barriers -> no vmcnt(0) drains; halo re-reads (1.23x)
// ride L1/L2 with XCD-contiguous block swizzle.

namespace {
constexpr int S = 4096;
constexpr int D = 512;
constexpr int K = 16;
constexpr int B = 32;
constexpr int CH = 16;                 // outputs per chunk
constexpr int NCH = 4;                 // chunks per block
constexpr int SEG = CH * NCH;          // 64 outputs per block
constexpr int FRAMES = CH + K - 1;     // 31 frames per chunk
constexpr int NW = 8;                  // waves per block
constexpr int SEGS_PER_ROW = S / SEG;  // 64
constexpr int NBLK = B * SEGS_PER_ROW; // 2048

__global__ __launch_bounds__(512)
void conv1d_kernel(const float* __restrict__ x,
                   const float* __restrict__ filt,
                   const float* __restrict__ bias,
                   float* __restrict__ out) {
  __shared__ float red[NCH][NW][CH];  // 2 KB

  const int tid = threadIdx.x;
  const int lane = tid & 63;
  const int wv = tid >> 6;
  const int d = wv * 64 + lane;  // this lane's single d

  // XCD-contiguous swizzle (NBLK % 8 == 0): neighbors share halo in one L2
  const int bid = blockIdx.x;
  const int lbid = (bid & 7) * (NBLK / 8) + (bid >> 3);
  const int b = lbid >> 6;                    // / SEGS_PER_ROW
  const int seg_start = (lbid & 63) * SEG;

  // filter column d in registers: 16 VGPR
  float w[K];
#pragma unroll
  for (int k = 0; k < K; ++k) w[k] = filt[k * D + d];

  const float* xp = x + (size_t)b * S * D + d;

  for (int c = 0; c < NCH; ++c) {
    const int i0 = seg_start + c * CH;
    float acc[CH];
#pragma unroll
    for (int o = 0; o < CH; ++o) acc[o] = 0.f;

#pragma unroll
    for (int tt = 0; tt < FRAMES; ++tt) {
      if (i0 + tt < S) {  // block-uniform; frames >= S are the zero padding
        const float xv = xp[(size_t)(i0 + tt) * D];
        const int klo = (tt - (CH - 1) > 0) ? (tt - (CH - 1)) : 0;
        const int khi = (tt < K - 1) ? tt : (K - 1);
#pragma unroll
        for (int k = klo; k <= khi; ++k)
          acc[tt - k] = fmaf(xv, w[k], acc[tt - k]);  // compile-time indices
      }
    }

    // 16 butterfly reductions over 64 lanes; lane o keeps output o
    float stv = 0.f;
#pragma unroll
    for (int o = 0; o < CH; ++o) {
      float s = acc[o];
#pragma unroll
      for (int m = 1; m < 64; m <<= 1) s += __shfl_xor(s, m, 64);
      if (lane == o) stv = s;
    }
    if (lane < CH) red[c][wv][lane] = stv;
  }

  __syncthreads();

  // combine the 8 wave-partials per output; one coalesced 256 B store
  if (tid < SEG) {
    const int c = tid >> 4, o = tid & 15;
    float v = 0.f;
#pragma unroll
    for (int wvi = 0; wvi < NW; ++wvi) v += red[c][wvi][o];
    out[(size_t)b * S + seg_start + tid] = v + bias[0];
  }
}
}  // namespace

extern "C" void kernel_launch(void* const* d_in, const int* in_sizes, int n_in,
                              void* d_out, int out_size, void* d_ws, size_t ws_size,
                              hipStream_t stream) {
  const float* x = (const float*)d_in[0];
  const float* filt = (const float*)d_in[1];
  const float* bias = (const float*)d_in[2];
  float* out = (float*)d_out;

  hipLaunchKernelGGL(conv1d_kernel, dim3(NBLK), dim3(512), 0, stream,
                     x, filt, bias, out);
}

// Round 5
// 89.287 us; speedup vs baseline: 3.9482x; 3.9482x over previous
//
#include <hip/hip_runtime.h>

// conv1d: out[b,i] = sum_{k<16,d<512} x[b,i+k,d] * w[k,d] + bias, zero-pad at end.
// R4: barrier-free straight-line streaming. Block = 256 thr (4 waves) owns a
// 128-output segment; lane owns 2 d's (float2 loads, 8 B); filter = 32 VGPR.
// Rolling 32-slot acc ring, all indices compile-time ((f-k)&31). NO branches
// in the hot path (R3's latency killer was per-frame conditionals blocking
// load hoisting); tail padding via template<bool TAIL> epilogue skip.
// Reduction: 8-output fold = 10 shuffles (vs 48 butterfly).

namespace {
constexpr int S = 4096;
constexpr int D = 512;
constexpr int K = 16;
constexpr int B = 32;
constexpr int SEG = 128;       // outputs per block
constexpr int NCH = SEG / 8;   // 16 chunks of 8 outputs
constexpr int SPR = S / SEG;   // 32 segments per row

// process one frame: load lane's float2 of frame (PBASE + FM*D), accumulate
// into ring slots ((FM - k) & 31). FM/KLO/KHI compile-time after unrolling.
#define FRAME(PBASE, FM, KLO, KHI)                                    \
  do {                                                                \
    const float2 xv =                                                 \
        *reinterpret_cast<const float2*>((PBASE) + (size_t)(FM) * D); \
    _Pragma("unroll")                                                 \
    for (int k = (KLO); k <= (KHI); ++k) {                            \
      const int sl = ((FM) - k) & 31;                                 \
      acc[sl] = fmaf(xv.x, w[k].x, acc[sl]);                          \
      acc[sl] = fmaf(xv.y, w[k].y, acc[sl]);                          \
    }                                                                 \
  } while (0)

// fold 8 completed ring slots (SB..SB+7 mod 32, SB compile-time) -> full
// 64-lane sums; lane l<8 stores output 4*(l&1)+2*((l>>1)&1)+((l>>2)&1).
#define FOLD(SB, C)                                                   \
  do {                                                                \
    float v[8];                                                       \
    _Pragma("unroll")                                                 \
    for (int i = 0; i < 8; ++i) {                                     \
      const int sl = ((SB) + i) & 31;                                 \
      v[i] = acc[sl];                                                 \
      acc[sl] = 0.f;                                                  \
    }                                                                 \
    const bool f0 = lane & 1, f1 = lane & 2, f2 = lane & 4;           \
    _Pragma("unroll")                                                 \
    for (int j = 0; j < 4; ++j) {                                     \
      const float sv = f0 ? v[j] : v[j + 4];                          \
      const float rv = __shfl_xor(sv, 1, 64);                         \
      v[j] = (f0 ? v[j + 4] : v[j]) + rv;                             \
    }                                                                 \
    _Pragma("unroll")                                                 \
    for (int j = 0; j < 2; ++j) {                                     \
      const float sv = f1 ? v[j] : v[j + 2];                          \
      const float rv = __shfl_xor(sv, 2, 64);                         \
      v[j] = (f1 ? v[j + 2] : v[j]) + rv;                             \
    }                                                                 \
    {                                                                 \
      const float sv = f2 ? v[0] : v[1];                              \
      const float rv = __shfl_xor(sv, 4, 64);                         \
      float tt = (f2 ? v[1] : v[0]) + rv;                             \
      tt += __shfl_xor(tt, 8, 64);                                    \
      tt += __shfl_xor(tt, 16, 64);                                   \
      tt += __shfl_xor(tt, 32, 64);                                   \
      if (lane < 8)                                                   \
        red[(C)][wv]                                                  \
           [4 * (lane & 1) + 2 * ((lane >> 1) & 1) + ((lane >> 2) & 1)] = tt; \
    }                                                                 \
  } while (0)

template <bool TAIL>
__global__ void conv1d_kernel(const float* __restrict__ x,
                              const float* __restrict__ filt,
                              const float* __restrict__ bias,
                              float* __restrict__ out, int seg_off) {
  __shared__ float red[NCH][4][8];  // 2 KB
  const int tid = threadIdx.x;
  const int lane = tid & 63;
  const int wv = tid >> 6;
  const int d0 = wv * 128 + lane * 2;
  const int b = blockIdx.y;
  const int seg = blockIdx.x + seg_off;
  const int seg_start = seg * SEG;

  // filter: lane's 2 d's for all 16 taps = 32 VGPR
  float2 w[K];
#pragma unroll
  for (int k = 0; k < K; ++k)
    w[k] = *reinterpret_cast<const float2*>(filt + k * D + d0);

  float acc[32];
#pragma unroll
  for (int i = 0; i < 32; ++i) acc[i] = 0.f;

  const float* px = x + ((size_t)b * S + seg_start) * D + d0;

  // ---- peel G=0: frames 0..31 (partial k-windows for f<15) ----
#pragma unroll
  for (int f = 0; f < 16; ++f) FRAME(px, f, 0, (f < 15 ? f : 15));
#pragma unroll
  for (int f = 16; f < 24; ++f) FRAME(px, f, 0, 15);
  FOLD(0, 0);
#pragma unroll
  for (int f = 24; f < 32; ++f) FRAME(px, f, 0, 15);
  FOLD(8, 1);

  // ---- main: G=1..3, frames 32G..32G+31, fold one chunk per 8 frames ----
  for (int G = 1; G <= 3; ++G) {
    const float* pg = px + (size_t)(32 * G) * D;
    const int cb = 4 * G - 2;
#pragma unroll
    for (int f = 0; f < 8; ++f) FRAME(pg, f, 0, 15);
    FOLD(16, cb);
#pragma unroll
    for (int f = 8; f < 16; ++f) FRAME(pg, f, 0, 15);
    FOLD(24, cb + 1);
#pragma unroll
    for (int f = 16; f < 24; ++f) FRAME(pg, f, 0, 15);
    FOLD(0, cb + 2);
#pragma unroll
    for (int f = 24; f < 32; ++f) FRAME(pg, f, 0, 15);
    FOLD(8, cb + 3);
  }

  // ---- epilogue: halo frames 128..142 (skipped entirely for TAIL blocks:
  // those frames are the reference's zero padding) + last two folds ----
  const float* pe = px + (size_t)128 * D;
  if constexpr (!TAIL) {
#pragma unroll
    for (int t = 0; t < 8; ++t) FRAME(pe, t, t + 1, 15);
  }
  FOLD(16, 14);
  if constexpr (!TAIL) {
#pragma unroll
    for (int t = 8; t < 15; ++t) FRAME(pe, t, t + 1, 15);
  }
  FOLD(24, 15);

  __syncthreads();

  // combine 4 wave-quarters + bias; one coalesced 512 B store per block
  if (tid < SEG) {
    const int c = tid >> 3, o = tid & 7;
    const float v =
        red[c][0][o] + red[c][1][o] + red[c][2][o] + red[c][3][o] + bias[0];
    out[(size_t)b * S + seg_start + tid] = v;
  }
}
}  // namespace

extern "C" void kernel_launch(void* const* d_in, const int* in_sizes, int n_in,
                              void* d_out, int out_size, void* d_ws, size_t ws_size,
                              hipStream_t stream) {
  const float* x = (const float*)d_in[0];
  const float* filt = (const float*)d_in[1];
  const float* bias = (const float*)d_in[2];
  float* out = (float*)d_out;

  // interior segments (0..30 of each row): no padding, branch-free
  hipLaunchKernelGGL((conv1d_kernel<false>), dim3(SPR - 1, B), dim3(256), 0,
                     stream, x, filt, bias, out, 0);
  // last segment of each row: epilogue frames are zero padding, skipped
  hipLaunchKernelGGL((conv1d_kernel<true>), dim3(1, B), dim3(256), 0,
                     stream, x, filt, bias, out, SPR - 1);
}